// Round 7
// baseline (400.224 us; speedup 1.0000x reference)
//
#include <hip/hip_runtime.h>

typedef unsigned short u16;
typedef short bf16x8 __attribute__((ext_vector_type(8)));
typedef float f32x4 __attribute__((ext_vector_type(4)));

#define BSZ 4
#define DD 1024
#define LLL 1024

__device__ __forceinline__ float bf2f(u16 u) {
    union { unsigned int i; float f; } w;
    w.i = ((unsigned int)u) << 16;
    return w.f;
}
__device__ __forceinline__ u16 f2bf(float f) {
    union { float fl; unsigned int i; } w;
    w.fl = f;
    w.i += 0x7fffu + ((w.i >> 16) & 1u);   // RNE
    return (u16)(w.i >> 16);
}

// async global->LDS, 16B per lane; LDS dst must be wave-uniform base + lane*16
__device__ __forceinline__ void load_lds16(const u16* g, u16* l) {
    __builtin_amdgcn_global_load_lds(
        (const __attribute__((address_space(1))) unsigned int*)g,
        (__attribute__((address_space(3))) unsigned int*)l, 16, 0, 0);
}

// ---- fused fp32->bf16 converts for x (4096 blk), Wi (2048), Wo (1024)
__global__ void cvt_all(const float* __restrict__ x, const float* __restrict__ Wi,
                        const float* __restrict__ Wo, u16* __restrict__ xb,
                        u16* __restrict__ wib, u16* __restrict__ wob) {
    int b = blockIdx.x;
    const float* in; u16* out;
    if (b < 4096)      { in = x;  out = xb; }
    else if (b < 6144) { in = Wi; out = wib; b -= 4096; }
    else               { in = Wo; out = wob; b -= 6144; }
    const size_t i = ((size_t)b * 256 + threadIdx.x) * 4;
    const float4 v = *(const float4*)(in + i);
    ushort4 o;
    o.x = f2bf(v.x); o.y = f2bf(v.y); o.z = f2bf(v.z); o.w = f2bf(v.w);
    *(ushort4*)(out + i) = o;
}

// ---- batched transpose+convert: in[z][R][C] f32 -> out[z][C][R] bf16
__global__ void transpose_cvt(const float* __restrict__ in, u16* __restrict__ out,
                              int R, int C) {
    __shared__ float tile[32][33];
    const size_t base = (size_t)blockIdx.z * R * C;
    const int c0 = blockIdx.x << 5, r0 = blockIdx.y << 5;
    const int tx = threadIdx.x & 31, ty = threadIdx.x >> 5;   // 256 thr = 32x8
    #pragma unroll
    for (int i = 0; i < 32; i += 8)
        tile[ty + i][tx] = in[base + (size_t)(r0 + ty + i) * C + c0 + tx];
    __syncthreads();
    #pragma unroll
    for (int i = 0; i < 32; i += 8)
        out[base + (size_t)(c0 + ty + i) * R + r0 + tx] = f2bf(tile[tx][ty + i]);
}

// ---- build vt[j][d][m], d padded to 80: d=64 ones-column (rowsum), 65..79 zero
__global__ void build_vt(const u16* __restrict__ proj, u16* __restrict__ vt) {
    __shared__ u16 tile[64][66];
    const int t = threadIdx.x;
    const int m0 = blockIdx.x << 6;
    const int jj = blockIdx.y;
    const int b = jj >> 4, k = jj & 15;
    const int tx = t & 63, ty = t >> 6;
    #pragma unroll
    for (int mi = ty; mi < 64; mi += 4)
        tile[mi][tx] = proj[(size_t)((m0 + mi) * BSZ + b) * 2048 + 1024 + k * 64 + tx];
    __syncthreads();
    #pragma unroll
    for (int di = ty; di < 64; di += 4)
        vt[((size_t)jj * 80 + di) * 1024 + m0 + tx] = tile[tx][di];
    #pragma unroll
    for (int di = 64 + ty; di < 80; di += 4)
        vt[((size_t)jj * 80 + di) * 1024 + m0 + tx] = (di == 64) ? 0x3F80 : 0;
}

// ---- generic batched bf16 NT-GEMM (round-6-proven): 128x128 tile, BK=64,
// XOR chunk swizzle, global_load_lds width=16.
template<int OUT_F32, int RELU>
__global__ __launch_bounds__(256, 2) void gemm_bf16_nt(
    const u16* __restrict__ A, int lda, long long sA,
    const u16* __restrict__ B, int ldb, long long sB,
    const float* __restrict__ bias, int sBias,
    void* __restrict__ C, int ldc, long long sC,
    int K)
{
    __shared__ u16 As[128 * 64];
    __shared__ u16 Bs[128 * 64];
    const int t = threadIdx.x;
    const int z = blockIdx.z;
    const u16* Ab = A + (size_t)z * sA + (size_t)blockIdx.x * 128 * lda;
    const u16* Bb = B + (size_t)z * sB + (size_t)blockIdx.y * 128 * ldb;
    const int wave = t >> 6, lane = t & 63;
    const int wrow = (wave >> 1) << 6;
    const int wcol = (wave & 1) << 6;
    const int lr = lane & 15, lq = lane >> 4;
    const int srow = t >> 3;
    const int gchunk = (t & 7) ^ (srow & 7);
    const u16* ApG = Ab + (size_t)srow * lda + gchunk * 8;
    const u16* BpG = Bb + (size_t)srow * ldb + gchunk * 8;
    u16* AsD = &As[t * 8];
    u16* BsD = &Bs[t * 8];
    const int o0 = ((lq    ) ^ (lr & 7)) * 8;
    const int o1 = ((lq + 4) ^ (lr & 7)) * 8;

    f32x4 acc[4][4];
    #pragma unroll
    for (int i = 0; i < 4; i++)
        #pragma unroll
        for (int j = 0; j < 4; j++)
            acc[i][j] = (f32x4){0.f, 0.f, 0.f, 0.f};

    for (int k0 = 0; k0 < K; k0 += 64) {
        __syncthreads();
        #pragma unroll
        for (int j = 0; j < 4; j++) {
            load_lds16(ApG + (size_t)j * 32 * lda + k0, AsD + j * 2048);
            load_lds16(BpG + (size_t)j * 32 * ldb + k0, BsD + j * 2048);
        }
        __syncthreads();
        #pragma unroll
        for (int s = 0; s < 2; s++) {
            const int oo = s ? o1 : o0;
            bf16x8 af[4], bfv[4];
            #pragma unroll
            for (int i = 0; i < 4; i++)
                af[i] = *(const bf16x8*)&As[(wrow + i * 16 + lr) * 64 + oo];
            #pragma unroll
            for (int j = 0; j < 4; j++)
                bfv[j] = *(const bf16x8*)&Bs[(wcol + j * 16 + lr) * 64 + oo];
            #pragma unroll
            for (int i = 0; i < 4; i++)
                #pragma unroll
                for (int j = 0; j < 4; j++)
                    acc[i][j] = __builtin_amdgcn_mfma_f32_16x16x32_bf16(
                        af[i], bfv[j], acc[i][j], 0, 0, 0);
        }
    }

    const float* biasb = bias + (size_t)z * sBias;
    const size_t row0 = (size_t)blockIdx.x * 128 + wrow + lq * 4;
    const int col0 = blockIdx.y * 128 + wcol + lr;
    #pragma unroll
    for (int j = 0; j < 4; j++) {
        const int col = col0 + j * 16;
        const float bb = biasb[col];
        #pragma unroll
        for (int i = 0; i < 4; i++) {
            #pragma unroll
            for (int r = 0; r < 4; r++) {
                const size_t row = row0 + i * 16 + r;
                float v = acc[i][j][r] + bb;
                if (RELU) v = fmaxf(v, 0.f);
                const size_t idx = row * (size_t)ldc + col;
                if (OUT_F32) ((float*)C)[(size_t)z * sC + idx] = v;
                else         ((u16*)C)[(size_t)z * sC + idx] = f2bf(v);
            }
        }
    }
}

// ---- fused hid+logits+softmax+PV (R6 structure + two fixes):
//  FIX 1 (T2): As2 stride-72 had an 8-way read bank conflict (start bank =
//    4*(lr+lq) mod 32 on every af ds_read_b128; R6 SQ_LDS_BANK_CONFLICT 9x).
//    Now stride-64 + XOR-chunk layout -- the SAME proven o0/o1 convention as
//    the GEMM As: elem (row,col) stored at chunk (col>>3)^(row&7). Write is
//    ds_write-fed (both sides controlled, rule 21 ok), write conflicts 2-way
//    (free), reads conflict-free.
//  FIX 2 (T4, surgical): split the staging drain. hid needs only W1s (2
//    loads, issued FIRST among the intrinsics); the 8 Bs loads aren't read
//    until logits. Counted wait: vmcnt(8) + raw s_barrier before hid (W1s
//    landed; Bs still in flight under the whole hid phase), then
//    vmcnt(0)+lgkmcnt(0) + raw s_barrier before logits (Bs landed + As2
//    ds_writes visible). One sched_barrier(0) after each raw barrier fences
//    LDS reads (rule 18); nothing else is pinned (not the R2 failure mode).
// LDS: As2 8192 + W1s 8192 + Bs 32768 = 49152 B. 2 blocks/CU (reg-capped).
__global__ __launch_bounds__(256, 2) void fused_attn(
    const u16* __restrict__ proj,   // (4096, 2048) bf16; q-half = cols 0..1023
    const u16* __restrict__ w1t,    // (16, 1024, 64) bf16 [k][h][d]
    const float* __restrict__ b1,   // (16, 1024) fp32
    const u16* __restrict__ w2t,    // (16, 1024, 1024) bf16 [k][m][h]
    const float* __restrict__ b2,   // (16, 1024) fp32
    const u16* __restrict__ vt,     // (64, 80, 1024) bf16
    u16* __restrict__ attn)         // (4096, 1024) bf16
{
    __shared__ u16 As2[64 * 64];    // computed hid tile, XOR-chunk     (8 KB)
    __shared__ u16 W1s[64 * 64];    // w1t slice staging                (8 KB)
    __shared__ u16 BsPs[256 * 64];  // Bs: w2t 256m x 64k / Ps overlay (32 KB)
    const int t = threadIdx.x;
    const int kq = blockIdx.x;      // 0..15 (x-dim -> XCD affinity)
    const int pair = blockIdx.y;    // 0..31
    const int wave = t >> 6, lane = t & 63;
    const int lr = lane & 15, lq = lane >> 4;
    const int wi = wave >> 1, wj = wave & 1;
    const int srow = t >> 3;                    // 0..31
    const int gch = (t & 7) ^ (srow & 7);       // XOR chunk swizzle
    const int o0 = ((lq    ) ^ (lr & 7)) * 8;
    const int o1 = ((lq + 4) ^ (lr & 7)) * 8;
    const int bv = kq >> 2;
    const int kvb = 4 * (kq & 3);               // kv = kvb + bq
    const u16* wb  = w2t + (size_t)kq * 1048576 + (size_t)srow * 1024 + gch * 8;
    const u16* w1b = w1t + (size_t)kq * 65536   + (size_t)srow * 64   + gch * 8;
    const float* b1b = b1 + kq * 1024;
    const float* b2b = b2 + kq * 1024;

    for (int part = 0; part < 2; part++) {
        const int s = part ? (63 - pair) : pair;
        const int l0 = s << 4;
        const int nt = (s >> 4) + 1;
        // q A-fragments for the in-kernel hid GEMM: wave w owns rt rows
        // w*16..+15 (bq=w); lane holds q[row=(l0+lr)*4+w][kq*64+kk*32+lq*8..]
        const u16* qsrc = proj + ((size_t)((l0 + lr) * 4 + wave)) * 2048
                        + kq * 64 + lq * 8;
        const bf16x8 qf0 = *(const bf16x8*)qsrc;
        const bf16x8 qf1 = *(const bf16x8*)(qsrc + 32);
        f32x4 o[5];
        #pragma unroll
        for (int j = 0; j < 5; j++) o[j] = (f32x4){0.f, 0.f, 0.f, 0.f};

        for (int mt = 0; mt < nt; mt++) {
            // ---- logits tile 64(rows) x 256(m), K=1024 (hid on the fly)
            f32x4 acc[2][8];
            #pragma unroll
            for (int i = 0; i < 2; i++)
                #pragma unroll
                for (int j = 0; j < 8; j++)
                    acc[i][j] = (f32x4){0.f, 0.f, 0.f, 0.f};
            for (int k0 = 0; k0 < 1024; k0 += 64) {
                __syncthreads();   // prior logits/PV reads of Bs/Ps/As2 done
                float b1v[4];
                #pragma unroll
                for (int j2 = 0; j2 < 4; j2++)
                    b1v[j2] = b1b[k0 + j2 * 16 + lr];
                // W1s intrinsics FIRST (program order among intrinsics) so
                // vmcnt(8) always covers them; then the 8 Bs loads.
                load_lds16(w1b + (size_t)k0 * 64,        &W1s[t * 8]);
                load_lds16(w1b + (size_t)k0 * 64 + 2048, &W1s[2048 + t * 8]);
                #pragma unroll
                for (int j2 = 0; j2 < 8; j2++)
                    load_lds16(wb + (size_t)(mt * 256 + j2 * 32) * 1024 + k0,
                               &BsPs[j2 * 2048 + t * 8]);
                // counted wait: W1s (+b1) done, 8 Bs loads stay in flight
                asm volatile("s_waitcnt vmcnt(8)" ::: "memory");
                __builtin_amdgcn_s_barrier();
                __builtin_amdgcn_sched_barrier(0);
                // -- hid slice: out[rt=w*16+lq*4+reg][h=k0+j2*16+lr]
                //    (runs while Bs streams into LDS)
                {
                    f32x4 ah[4];
                    #pragma unroll
                    for (int j2 = 0; j2 < 4; j2++)
                        ah[j2] = (f32x4){0.f, 0.f, 0.f, 0.f};
                    #pragma unroll
                    for (int kk = 0; kk < 2; kk++) {
                        const int oo = kk ? o1 : o0;
                        #pragma unroll
                        for (int j2 = 0; j2 < 4; j2++) {
                            const bf16x8 bw = *(const bf16x8*)
                                &W1s[(j2 * 16 + lr) * 64 + oo];
                            ah[j2] = __builtin_amdgcn_mfma_f32_16x16x32_bf16(
                                kk ? qf1 : qf0, bw, ah[j2], 0, 0, 0);
                        }
                    }
                    const int rtb = wave * 16 + lq * 4;
                    #pragma unroll
                    for (int j2 = 0; j2 < 4; j2++) {
                        #pragma unroll
                        for (int rg = 0; rg < 4; rg++) {
                            const float v = fmaxf(ah[j2][rg] + b1v[j2], 0.f);
                            const int row = rtb + rg;
                            As2[row * 64 +
                                (((j2 * 2 + (lr >> 3)) ^ (row & 7)) << 3) +
                                (lr & 7)] = f2bf(v);
                        }
                    }
                }
                // full drain: Bs landed + As2 ds_writes visible to all waves
                asm volatile("s_waitcnt vmcnt(0) lgkmcnt(0)" ::: "memory");
                __builtin_amdgcn_s_barrier();
                __builtin_amdgcn_sched_barrier(0);
                #pragma unroll
                for (int s2 = 0; s2 < 2; s2++) {
                    const int oo = s2 ? o1 : o0;
                    bf16x8 af[2], bfv[8];
                    #pragma unroll
                    for (int i = 0; i < 2; i++)
                        af[i] = *(const bf16x8*)
                            &As2[(wi * 32 + i * 16 + lr) * 64 + oo];
                    #pragma unroll
                    for (int j = 0; j < 8; j++)
                        bfv[j] = *(const bf16x8*)
                            &BsPs[(wj * 128 + j * 16 + lr) * 64 + oo];
                    #pragma unroll
                    for (int i = 0; i < 2; i++)
                        #pragma unroll
                        for (int j = 0; j < 8; j++)
                            acc[i][j] = __builtin_amdgcn_mfma_f32_16x16x32_bf16(
                                af[i], bfv[j], acc[i][j], 0, 0, 0);
                }
            }
            // ---- +b2, causal compare, exp -> Ps (bf16, overlaid on Bs)
            __syncthreads();   // all waves' last Bs MFMA reads complete
            float b2v[8];
            #pragma unroll
            for (int j = 0; j < 8; j++)
                b2v[j] = b2b[mt * 256 + wj * 128 + j * 16 + lr];
            #pragma unroll
            for (int i = 0; i < 2; i++) {
                #pragma unroll
                for (int j = 0; j < 8; j++) {
                    const int cp = wj * 128 + j * 16 + lr;
                    const int m = mt * 256 + cp;
                    const int cb = cp & 7;       // elem within 8-chunk
                    const int cc = cp >> 3;      // chunk index
                    #pragma unroll
                    for (int rr = 0; rr < 4; rr++) {
                        const int rt = wi * 32 + i * 16 + lq * 4 + rr;
                        const int l = l0 + lq * 4 + rr;   // rt&15 == lq*4+rr
                        const float e = __expf(acc[i][j][rr] + b2v[j]);
                        BsPs[rt * 256 + cb + ((cc ^ (rt & 7)) << 3)]
                            = (m <= l) ? f2bf(e) : (u16)0;
                    }
                }
            }
            __syncthreads();
            // ---- O += P @ V^T: wave w owns bq = w (rows w*16..w*16+15)
            {
                const u16* vbb = vt + (size_t)(kq * 4 + wave) * 80 * 1024
                               + (size_t)mt * 256 + lq * 8;
                const int rt = wave * 16 + lr;
                #pragma unroll
                for (int kc = 0; kc < 8; kc++) {
                    const bf16x8 a = *(const bf16x8*)
                        &BsPs[rt * 256 + ((((kc << 2) + lq) ^ (rt & 7)) << 3)];
                    #pragma unroll
                    for (int j = 0; j < 5; j++) {
                        const bf16x8 b = *(const bf16x8*)
                            (vbb + (size_t)(j * 16 + lr) * 1024 + kc * 32);
                        o[j] = __builtin_amdgcn_mfma_f32_16x16x32_bf16(
                            a, b, o[j], 0, 0, 0);
                    }
                }
            }
        }
        // ---- normalize by rowsum (ones-column d=64 -> o[4], lanes lr==0)
        {
            const int bq = wave;
            float sden[4];
            #pragma unroll
            for (int rr = 0; rr < 4; rr++)
                sden[rr] = __shfl(o[4][rr], lq << 4);
            #pragma unroll
            for (int j = 0; j < 4; j++) {
                #pragma unroll
                for (int rr = 0; rr < 4; rr++) {
                    const int l = l0 + lq * 4 + rr;
                    attn[(size_t)(l * BSZ + bv) * 1024 + (kvb + bq) * 64 + j * 16 + lr]
                        = f2bf(o[j][rr] / sden[rr]);
                }
            }
        }
    }
}

extern "C" void kernel_launch(void* const* d_in, const int* in_sizes, int n_in,
                              void* d_out, int out_size, void* d_ws, size_t ws_size,
                              hipStream_t stream)
{
    (void)in_sizes; (void)n_in; (void)out_size; (void)ws_size;
    const float* x  = (const float*)d_in[0];
    const float* Wi = (const float*)d_in[2];
    const float* bi = (const float*)d_in[3];
    const float* w1 = (const float*)d_in[4];
    const float* b1 = (const float*)d_in[5];
    const float* w2 = (const float*)d_in[6];
    const float* b2 = (const float*)d_in[7];
    const float* Wo = (const float*)d_in[8];
    const float* bo = (const float*)d_in[9];

    // ws layout (bf16 elems): 46 MB used <= 256 MiB (hid no longer stored)
    u16* x_b    = (u16*)d_ws;                  // 4096x1024       = 4M
    u16* Wi_b   = x_b    + (size_t)4194304;    // 2048x1024       = 2M
    u16* w1t    = Wi_b   + (size_t)2097152;    // 16 x 1024x64    = 1M
    u16* w2t    = w1t    + (size_t)1048576;    // 16 x 1024x1024  = 16M
    u16* Wo_b   = w2t    + (size_t)16777216;   // 1024x1024       = 1M
    u16* proj_b = Wo_b   + (size_t)1048576;    // 4096x2048       = 8M
    u16* attn_b = proj_b + (size_t)8388608;    // 4096x1024       = 4M
    u16* vt     = attn_b + (size_t)4194304;    // 64 x 80 x 1024  = 5M

    // ---- prep
    cvt_all<<<7168, 256, 0, stream>>>(x, Wi, Wo, x_b, Wi_b, Wo_b);
    transpose_cvt<<<dim3(32,  2, 16), 256, 0, stream>>>(w1, w1t, 64,   1024);
    transpose_cvt<<<dim3(32, 32, 16), 256, 0, stream>>>(w2, w2t, 1024, 1024);

    // ---- proj = x @ Wi.T + bi  -> bf16 (4096 x 2048)
    gemm_bf16_nt<0, 0><<<dim3(32, 16, 1), 256, 0, stream>>>(
        x_b, 1024, 0, Wi_b, 1024, 0, bi, 0, (void*)proj_b, 2048, 0, 1024);

    // ---- vt[j][d(80)][m] from proj's v-half (with ones-column at d=64)
    build_vt<<<dim3(16, 64), 256, 0, stream>>>(proj_b, vt);

    // ---- fused hid + logits + softmax + PV (hid in-kernel; As2 XOR layout,
    //      counted split-drain so Bs loads fly under the hid phase)
    fused_attn<<<dim3(16, 32), 256, 0, stream>>>(
        proj_b, w1t, b1, w2t, b2, vt, attn_b);

    // ---- out = attn @ Wo.T + bo -> fp32 (4096 x 1024)
    gemm_bf16_nt<1, 0><<<dim3(32, 8, 1), 256, 0, stream>>>(
        attn_b, 1024, 0, Wo_b, 1024, 0, bo, 0, d_out, 1024, 0, 1024);
}

// Round 8
// 392.017 us; speedup vs baseline: 1.0209x; 1.0209x over previous
//
#include <hip/hip_runtime.h>

typedef unsigned short u16;
typedef short bf16x8 __attribute__((ext_vector_type(8)));
typedef float f32x4 __attribute__((ext_vector_type(4)));

#define BSZ 4
#define DD 1024
#define LLL 1024

__device__ __forceinline__ float bf2f(u16 u) {
    union { unsigned int i; float f; } w;
    w.i = ((unsigned int)u) << 16;
    return w.f;
}
__device__ __forceinline__ u16 f2bf(float f) {
    union { float fl; unsigned int i; } w;
    w.fl = f;
    w.i += 0x7fffu + ((w.i >> 16) & 1u);   // RNE
    return (u16)(w.i >> 16);
}

// async global->LDS, 16B per lane; LDS dst must be wave-uniform base + lane*16
__device__ __forceinline__ void load_lds16(const u16* g, u16* l) {
    __builtin_amdgcn_global_load_lds(
        (const __attribute__((address_space(1))) unsigned int*)g,
        (__attribute__((address_space(3))) unsigned int*)l, 16, 0, 0);
}

// ---- fused fp32->bf16 converts for x (4096 blk), Wi (2048), Wo (1024)
__global__ void cvt_all(const float* __restrict__ x, const float* __restrict__ Wi,
                        const float* __restrict__ Wo, u16* __restrict__ xb,
                        u16* __restrict__ wib, u16* __restrict__ wob) {
    int b = blockIdx.x;
    const float* in; u16* out;
    if (b < 4096)      { in = x;  out = xb; }
    else if (b < 6144) { in = Wi; out = wib; b -= 4096; }
    else               { in = Wo; out = wob; b -= 6144; }
    const size_t i = ((size_t)b * 256 + threadIdx.x) * 4;
    const float4 v = *(const float4*)(in + i);
    ushort4 o;
    o.x = f2bf(v.x); o.y = f2bf(v.y); o.z = f2bf(v.z); o.w = f2bf(v.w);
    *(ushort4*)(out + i) = o;
}

// ---- batched transpose+convert: in[z][R][C] f32 -> out[z][C][R] bf16
__global__ void transpose_cvt(const float* __restrict__ in, u16* __restrict__ out,
                              int R, int C) {
    __shared__ float tile[32][33];
    const size_t base = (size_t)blockIdx.z * R * C;
    const int c0 = blockIdx.x << 5, r0 = blockIdx.y << 5;
    const int tx = threadIdx.x & 31, ty = threadIdx.x >> 5;   // 256 thr = 32x8
    #pragma unroll
    for (int i = 0; i < 32; i += 8)
        tile[ty + i][tx] = in[base + (size_t)(r0 + ty + i) * C + c0 + tx];
    __syncthreads();
    #pragma unroll
    for (int i = 0; i < 32; i += 8)
        out[base + (size_t)(c0 + ty + i) * R + r0 + tx] = f2bf(tile[tx][ty + i]);
}

// ---- build vt[j][d][m], d padded to 80: d=64 ones-column (rowsum), 65..79 zero
__global__ void build_vt(const u16* __restrict__ proj, u16* __restrict__ vt) {
    __shared__ u16 tile[64][66];
    const int t = threadIdx.x;
    const int m0 = blockIdx.x << 6;
    const int jj = blockIdx.y;
    const int b = jj >> 4, k = jj & 15;
    const int tx = t & 63, ty = t >> 6;
    #pragma unroll
    for (int mi = ty; mi < 64; mi += 4)
        tile[mi][tx] = proj[(size_t)((m0 + mi) * BSZ + b) * 2048 + 1024 + k * 64 + tx];
    __syncthreads();
    #pragma unroll
    for (int di = ty; di < 64; di += 4)
        vt[((size_t)jj * 80 + di) * 1024 + m0 + tx] = tile[tx][di];
    #pragma unroll
    for (int di = 64 + ty; di < 80; di += 4)
        vt[((size_t)jj * 80 + di) * 1024 + m0 + tx] = (di == 64) ? 0x3F80 : 0;
}

// ---- generic batched bf16 NT-GEMM (round-6-proven): 128x128 tile, BK=64,
// XOR chunk swizzle, global_load_lds width=16.
template<int OUT_F32, int RELU>
__global__ __launch_bounds__(256, 2) void gemm_bf16_nt(
    const u16* __restrict__ A, int lda, long long sA,
    const u16* __restrict__ B, int ldb, long long sB,
    const float* __restrict__ bias, int sBias,
    void* __restrict__ C, int ldc, long long sC,
    int K)
{
    __shared__ u16 As[128 * 64];
    __shared__ u16 Bs[128 * 64];
    const int t = threadIdx.x;
    const int z = blockIdx.z;
    const u16* Ab = A + (size_t)z * sA + (size_t)blockIdx.x * 128 * lda;
    const u16* Bb = B + (size_t)z * sB + (size_t)blockIdx.y * 128 * ldb;
    const int wave = t >> 6, lane = t & 63;
    const int wrow = (wave >> 1) << 6;
    const int wcol = (wave & 1) << 6;
    const int lr = lane & 15, lq = lane >> 4;
    const int srow = t >> 3;
    const int gchunk = (t & 7) ^ (srow & 7);
    const u16* ApG = Ab + (size_t)srow * lda + gchunk * 8;
    const u16* BpG = Bb + (size_t)srow * ldb + gchunk * 8;
    u16* AsD = &As[t * 8];
    u16* BsD = &Bs[t * 8];
    const int o0 = ((lq    ) ^ (lr & 7)) * 8;
    const int o1 = ((lq + 4) ^ (lr & 7)) * 8;

    f32x4 acc[4][4];
    #pragma unroll
    for (int i = 0; i < 4; i++)
        #pragma unroll
        for (int j = 0; j < 4; j++)
            acc[i][j] = (f32x4){0.f, 0.f, 0.f, 0.f};

    for (int k0 = 0; k0 < K; k0 += 64) {
        __syncthreads();
        #pragma unroll
        for (int j = 0; j < 4; j++) {
            load_lds16(ApG + (size_t)j * 32 * lda + k0, AsD + j * 2048);
            load_lds16(BpG + (size_t)j * 32 * ldb + k0, BsD + j * 2048);
        }
        __syncthreads();
        #pragma unroll
        for (int s = 0; s < 2; s++) {
            const int oo = s ? o1 : o0;
            bf16x8 af[4], bfv[4];
            #pragma unroll
            for (int i = 0; i < 4; i++)
                af[i] = *(const bf16x8*)&As[(wrow + i * 16 + lr) * 64 + oo];
            #pragma unroll
            for (int j = 0; j < 4; j++)
                bfv[j] = *(const bf16x8*)&Bs[(wcol + j * 16 + lr) * 64 + oo];
            #pragma unroll
            for (int i = 0; i < 4; i++)
                #pragma unroll
                for (int j = 0; j < 4; j++)
                    acc[i][j] = __builtin_amdgcn_mfma_f32_16x16x32_bf16(
                        af[i], bfv[j], acc[i][j], 0, 0, 0);
        }
    }

    const float* biasb = bias + (size_t)z * sBias;
    const size_t row0 = (size_t)blockIdx.x * 128 + wrow + lq * 4;
    const int col0 = blockIdx.y * 128 + wcol + lr;
    #pragma unroll
    for (int j = 0; j < 4; j++) {
        const int col = col0 + j * 16;
        const float bb = biasb[col];
        #pragma unroll
        for (int i = 0; i < 4; i++) {
            #pragma unroll
            for (int r = 0; r < 4; r++) {
                const size_t row = row0 + i * 16 + r;
                float v = acc[i][j][r] + bb;
                if (RELU) v = fmaxf(v, 0.f);
                const size_t idx = row * (size_t)ldc + col;
                if (OUT_F32) ((float*)C)[(size_t)z * sC + idx] = v;
                else         ((u16*)C)[(size_t)z * sC + idx] = f2bf(v);
            }
        }
    }
}

// ---- fused hid+logits+softmax+PV (R6 structure + two fixes):
//  FIX 1 (T2): As2 stride-72 had an 8-way read bank conflict (start bank =
//    4*(lr+lq) mod 32 on every af ds_read_b128; R6 SQ_LDS_BANK_CONFLICT 9x).
//    Now stride-64 + XOR-chunk layout -- the SAME proven o0/o1 convention as
//    the GEMM As: elem (row,col) stored at chunk (col>>3)^(row&7). Write is
//    ds_write-fed (both sides controlled, rule 21 ok), write conflicts 2-way
//    (free), reads conflict-free.
//  FIX 2 (T4, surgical): split the staging drain. hid needs only W1s (2
//    loads, issued FIRST among the intrinsics); the 8 Bs loads aren't read
//    until logits. Counted wait: vmcnt(8) + raw s_barrier before hid (W1s
//    landed; Bs still in flight under the whole hid phase), then
//    vmcnt(0)+lgkmcnt(0) + raw s_barrier before logits (Bs landed + As2
//    ds_writes visible). One sched_barrier(0) after each raw barrier fences
//    LDS reads (rule 18); nothing else is pinned (not the R2 failure mode).
// LDS: As2 8192 + W1s 8192 + Bs 32768 = 49152 B. 2 blocks/CU (reg-capped).
__global__ __launch_bounds__(256, 2) void fused_attn(
    const u16* __restrict__ proj,   // (4096, 2048) bf16; q-half = cols 0..1023
    const u16* __restrict__ w1t,    // (16, 1024, 64) bf16 [k][h][d]
    const float* __restrict__ b1,   // (16, 1024) fp32
    const u16* __restrict__ w2t,    // (16, 1024, 1024) bf16 [k][m][h]
    const float* __restrict__ b2,   // (16, 1024) fp32
    const u16* __restrict__ vt,     // (64, 80, 1024) bf16
    u16* __restrict__ attn)         // (4096, 1024) bf16
{
    __shared__ u16 As2[64 * 64];    // computed hid tile, XOR-chunk     (8 KB)
    __shared__ u16 W1s[64 * 64];    // w1t slice staging                (8 KB)
    __shared__ u16 BsPs[256 * 64];  // Bs: w2t 256m x 64k / Ps overlay (32 KB)
    const int t = threadIdx.x;
    const int kq = blockIdx.x;      // 0..15 (x-dim -> XCD affinity)
    const int pair = blockIdx.y;    // 0..31
    const int wave = t >> 6, lane = t & 63;
    const int lr = lane & 15, lq = lane >> 4;
    const int wi = wave >> 1, wj = wave & 1;
    const int srow = t >> 3;                    // 0..31
    const int gch = (t & 7) ^ (srow & 7);       // XOR chunk swizzle
    const int o0 = ((lq    ) ^ (lr & 7)) * 8;
    const int o1 = ((lq + 4) ^ (lr & 7)) * 8;
    const int bv = kq >> 2;
    const int kvb = 4 * (kq & 3);               // kv = kvb + bq
    const u16* wb  = w2t + (size_t)kq * 1048576 + (size_t)srow * 1024 + gch * 8;
    const u16* w1b = w1t + (size_t)kq * 65536   + (size_t)srow * 64   + gch * 8;
    const float* b1b = b1 + kq * 1024;
    const float* b2b = b2 + kq * 1024;

    for (int part = 0; part < 2; part++) {
        const int s = part ? (63 - pair) : pair;
        const int l0 = s << 4;
        const int nt = (s >> 4) + 1;
        // q A-fragments for the in-kernel hid GEMM: wave w owns rt rows
        // w*16..+15 (bq=w); lane holds q[row=(l0+lr)*4+w][kq*64+kk*32+lq*8..]
        const u16* qsrc = proj + ((size_t)((l0 + lr) * 4 + wave)) * 2048
                        + kq * 64 + lq * 8;
        const bf16x8 qf0 = *(const bf16x8*)qsrc;
        const bf16x8 qf1 = *(const bf16x8*)(qsrc + 32);
        f32x4 o[5];
        #pragma unroll
        for (int j = 0; j < 5; j++) o[j] = (f32x4){0.f, 0.f, 0.f, 0.f};

        for (int mt = 0; mt < nt; mt++) {
            // ---- logits tile 64(rows) x 256(m), K=1024 (hid on the fly)
            f32x4 acc[2][8];
            #pragma unroll
            for (int i = 0; i < 2; i++)
                #pragma unroll
                for (int j = 0; j < 8; j++)
                    acc[i][j] = (f32x4){0.f, 0.f, 0.f, 0.f};
            for (int k0 = 0; k0 < 1024; k0 += 64) {
                __syncthreads();   // prior logits/PV reads of Bs/Ps/As2 done
                float b1v[4];
                #pragma unroll
                for (int j2 = 0; j2 < 4; j2++)
                    b1v[j2] = b1b[k0 + j2 * 16 + lr];
                // W1s intrinsics FIRST (program order among intrinsics) so
                // vmcnt(8) always covers them; then the 8 Bs loads.
                load_lds16(w1b + (size_t)k0 * 64,        &W1s[t * 8]);
                load_lds16(w1b + (size_t)k0 * 64 + 2048, &W1s[2048 + t * 8]);
                #pragma unroll
                for (int j2 = 0; j2 < 8; j2++)
                    load_lds16(wb + (size_t)(mt * 256 + j2 * 32) * 1024 + k0,
                               &BsPs[j2 * 2048 + t * 8]);
                // counted wait: W1s (+b1) done, 8 Bs loads stay in flight
                asm volatile("s_waitcnt vmcnt(8)" ::: "memory");
                __builtin_amdgcn_s_barrier();
                __builtin_amdgcn_sched_barrier(0);
                // -- hid slice: out[rt=w*16+lq*4+reg][h=k0+j2*16+lr]
                //    (runs while Bs streams into LDS)
                {
                    f32x4 ah[4];
                    #pragma unroll
                    for (int j2 = 0; j2 < 4; j2++)
                        ah[j2] = (f32x4){0.f, 0.f, 0.f, 0.f};
                    #pragma unroll
                    for (int kk = 0; kk < 2; kk++) {
                        const int oo = kk ? o1 : o0;
                        #pragma unroll
                        for (int j2 = 0; j2 < 4; j2++) {
                            const bf16x8 bw = *(const bf16x8*)
                                &W1s[(j2 * 16 + lr) * 64 + oo];
                            ah[j2] = __builtin_amdgcn_mfma_f32_16x16x32_bf16(
                                kk ? qf1 : qf0, bw, ah[j2], 0, 0, 0);
                        }
                    }
                    const int rtb = wave * 16 + lq * 4;
                    #pragma unroll
                    for (int j2 = 0; j2 < 4; j2++) {
                        #pragma unroll
                        for (int rg = 0; rg < 4; rg++) {
                            const float v = fmaxf(ah[j2][rg] + b1v[j2], 0.f);
                            const int row = rtb + rg;
                            As2[row * 64 +
                                (((j2 * 2 + (lr >> 3)) ^ (row & 7)) << 3) +
                                (lr & 7)] = f2bf(v);
                        }
                    }
                }
                // full drain: Bs landed + As2 ds_writes visible to all waves
                asm volatile("s_waitcnt vmcnt(0) lgkmcnt(0)" ::: "memory");
                __builtin_amdgcn_s_barrier();
                __builtin_amdgcn_sched_barrier(0);
                #pragma unroll
                for (int s2 = 0; s2 < 2; s2++) {
                    const int oo = s2 ? o1 : o0;
                    bf16x8 af[2], bfv[8];
                    #pragma unroll
                    for (int i = 0; i < 2; i++)
                        af[i] = *(const bf16x8*)
                            &As2[(wi * 32 + i * 16 + lr) * 64 + oo];
                    #pragma unroll
                    for (int j = 0; j < 8; j++)
                        bfv[j] = *(const bf16x8*)
                            &BsPs[(wj * 128 + j * 16 + lr) * 64 + oo];
                    #pragma unroll
                    for (int i = 0; i < 2; i++)
                        #pragma unroll
                        for (int j = 0; j < 8; j++)
                            acc[i][j] = __builtin_amdgcn_mfma_f32_16x16x32_bf16(
                                af[i], bfv[j], acc[i][j], 0, 0, 0);
                }
            }
            // ---- +b2, causal compare, exp -> Ps (bf16, overlaid on Bs)
            __syncthreads();   // all waves' last Bs MFMA reads complete
            float b2v[8];
            #pragma unroll
            for (int j = 0; j < 8; j++)
                b2v[j] = b2b[mt * 256 + wj * 128 + j * 16 + lr];
            #pragma unroll
            for (int i = 0; i < 2; i++) {
                #pragma unroll
                for (int j = 0; j < 8; j++) {
                    const int cp = wj * 128 + j * 16 + lr;
                    const int m = mt * 256 + cp;
                    const int cb = cp & 7;       // elem within 8-chunk
                    const int cc = cp >> 3;      // chunk index
                    #pragma unroll
                    for (int rr = 0; rr < 4; rr++) {
                        const int rt = wi * 32 + i * 16 + lq * 4 + rr;
                        const int l = l0 + lq * 4 + rr;   // rt&15 == lq*4+rr
                        const float e = __expf(acc[i][j][rr] + b2v[j]);
                        BsPs[rt * 256 + cb + ((cc ^ (rt & 7)) << 3)]
                            = (m <= l) ? f2bf(e) : (u16)0;
                    }
                }
            }
            __syncthreads();
            // ---- O += P @ V^T: wave w owns bq = w (rows w*16..w*16+15)
            {
                const u16* vbb = vt + (size_t)(kq * 4 + wave) * 80 * 1024
                               + (size_t)mt * 256 + lq * 8;
                const int rt = wave * 16 + lr;
                #pragma unroll
                for (int kc = 0; kc < 8; kc++) {
                    const bf16x8 a = *(const bf16x8*)
                        &BsPs[rt * 256 + ((((kc << 2) + lq) ^ (rt & 7)) << 3)];
                    #pragma unroll
                    for (int j = 0; j < 5; j++) {
                        const bf16x8 b = *(const bf16x8*)
                            (vbb + (size_t)(j * 16 + lr) * 1024 + kc * 32);
                        o[j] = __builtin_amdgcn_mfma_f32_16x16x32_bf16(
                            a, b, o[j], 0, 0, 0);
                    }
                }
            }
        }
        // ---- normalize by rowsum (ones-column d=64 -> o[4], lanes lr==0)
        {
            const int bq = wave;
            float sden[4];
            #pragma unroll
            for (int rr = 0; rr < 4; rr++)
                sden[rr] = __shfl(o[4][rr], lq << 4);
            #pragma unroll
            for (int j = 0; j < 4; j++) {
                #pragma unroll
                for (int rr = 0; rr < 4; rr++) {
                    const int l = l0 + lq * 4 + rr;
                    attn[(size_t)(l * BSZ + bv) * 1024 + (kvb + bq) * 64 + j * 16 + lr]
                        = f2bf(o[j][rr] / sden[rr]);
                }
            }
        }
    }
}

extern "C" void kernel_launch(void* const* d_in, const int* in_sizes, int n_in,
                              void* d_out, int out_size, void* d_ws, size_t ws_size,
                              hipStream_t stream)
{
    (void)in_sizes; (void)n_in; (void)out_size; (void)ws_size;
    const float* x  = (const float*)d_in[0];
    const float* Wi = (const float*)d_in[2];
    const float* bi = (const float*)d_in[3];
    const float* w1 = (const float*)d_in[4];
    const float* b1 = (const float*)d_in[5];
    const float* w2 = (const float*)d_in[6];
    const float* b2 = (const float*)d_in[7];
    const float* Wo = (const float*)d_in[8];
    const float* bo = (const float*)d_in[9];

    // ws layout (bf16 elems): 46 MB used <= 256 MiB (hid no longer stored)
    u16* x_b    = (u16*)d_ws;                  // 4096x1024       = 4M
    u16* Wi_b   = x_b    + (size_t)4194304;    // 2048x1024       = 2M
    u16* w1t    = Wi_b   + (size_t)2097152;    // 16 x 1024x64    = 1M
    u16* w2t    = w1t    + (size_t)1048576;    // 16 x 1024x1024  = 16M
    u16* Wo_b   = w2t    + (size_t)16777216;   // 1024x1024       = 1M
    u16* proj_b = Wo_b   + (size_t)1048576;    // 4096x2048       = 8M
    u16* attn_b = proj_b + (size_t)8388608;    // 4096x1024       = 4M
    u16* vt     = attn_b + (size_t)4194304;    // 64 x 80 x 1024  = 5M

    // ---- prep
    cvt_all<<<7168, 256, 0, stream>>>(x, Wi, Wo, x_b, Wi_b, Wo_b);
    transpose_cvt<<<dim3(32,  2, 16), 256, 0, stream>>>(w1, w1t, 64,   1024);
    transpose_cvt<<<dim3(32, 32, 16), 256, 0, stream>>>(w2, w2t, 1024, 1024);

    // ---- proj = x @ Wi.T + bi  -> bf16 (4096 x 2048)
    gemm_bf16_nt<0, 0><<<dim3(32, 16, 1), 256, 0, stream>>>(
        x_b, 1024, 0, Wi_b, 1024, 0, bi, 0, (void*)proj_b, 2048, 0, 1024);

    // ---- vt[j][d(80)][m] from proj's v-half (with ones-column at d=64)
    build_vt<<<dim3(16, 64), 256, 0, stream>>>(proj_b, vt);

    // ---- fused hid + logits + softmax + PV (hid in-kernel; As2 XOR layout,
    //      counted split-drain so Bs loads fly under the hid phase)
    fused_attn<<<dim3(16, 32), 256, 0, stream>>>(
        proj_b, w1t, b1, w2t, b2, vt, attn_b);

    // ---- out = attn @ Wo.T + bo -> fp32 (4096 x 1024)
    gemm_bf16_nt<1, 0><<<dim3(32, 8, 1), 256, 0, stream>>>(
        attn_b, 1024, 0, Wo_b, 1024, 0, bo, 0, d_out, 1024, 0, 1024);
}

// Round 9
// 379.364 us; speedup vs baseline: 1.0550x; 1.0334x over previous
//
#include <hip/hip_runtime.h>

typedef unsigned short u16;
typedef short bf16x8 __attribute__((ext_vector_type(8)));
typedef float f32x4 __attribute__((ext_vector_type(4)));

#define BSZ 4
#define DD 1024
#define LLL 1024

__device__ __forceinline__ float bf2f(u16 u) {
    union { unsigned int i; float f; } w;
    w.i = ((unsigned int)u) << 16;
    return w.f;
}
__device__ __forceinline__ u16 f2bf(float f) {
    union { float fl; unsigned int i; } w;
    w.fl = f;
    w.i += 0x7fffu + ((w.i >> 16) & 1u);   // RNE
    return (u16)(w.i >> 16);
}

// async global->LDS, 16B per lane; LDS dst must be wave-uniform base + lane*16
__device__ __forceinline__ void load_lds16(const u16* g, u16* l) {
    __builtin_amdgcn_global_load_lds(
        (const __attribute__((address_space(1))) unsigned int*)g,
        (__attribute__((address_space(3))) unsigned int*)l, 16, 0, 0);
}

// ---- fused fp32->bf16 converts for x (4096 blk), Wi (2048), Wo (1024)
__global__ void cvt_all(const float* __restrict__ x, const float* __restrict__ Wi,
                        const float* __restrict__ Wo, u16* __restrict__ xb,
                        u16* __restrict__ wib, u16* __restrict__ wob) {
    int b = blockIdx.x;
    const float* in; u16* out;
    if (b < 4096)      { in = x;  out = xb; }
    else if (b < 6144) { in = Wi; out = wib; b -= 4096; }
    else               { in = Wo; out = wob; b -= 6144; }
    const size_t i = ((size_t)b * 256 + threadIdx.x) * 4;
    const float4 v = *(const float4*)(in + i);
    ushort4 o;
    o.x = f2bf(v.x); o.y = f2bf(v.y); o.z = f2bf(v.z); o.w = f2bf(v.w);
    *(ushort4*)(out + i) = o;
}

// ---- batched transpose+convert: in[z][R][C] f32 -> out[z][C][R] bf16
__global__ void transpose_cvt(const float* __restrict__ in, u16* __restrict__ out,
                              int R, int C) {
    __shared__ float tile[32][33];
    const size_t base = (size_t)blockIdx.z * R * C;
    const int c0 = blockIdx.x << 5, r0 = blockIdx.y << 5;
    const int tx = threadIdx.x & 31, ty = threadIdx.x >> 5;   // 256 thr = 32x8
    #pragma unroll
    for (int i = 0; i < 32; i += 8)
        tile[ty + i][tx] = in[base + (size_t)(r0 + ty + i) * C + c0 + tx];
    __syncthreads();
    #pragma unroll
    for (int i = 0; i < 32; i += 8)
        out[base + (size_t)(c0 + ty + i) * R + r0 + tx] = f2bf(tile[tx][ty + i]);
}

// ---- build vt[j][d][m], d padded to 80: d=64 ones-column (rowsum), 65..79 zero
__global__ void build_vt(const u16* __restrict__ proj, u16* __restrict__ vt) {
    __shared__ u16 tile[64][66];
    const int t = threadIdx.x;
    const int m0 = blockIdx.x << 6;
    const int jj = blockIdx.y;
    const int b = jj >> 4, k = jj & 15;
    const int tx = t & 63, ty = t >> 6;
    #pragma unroll
    for (int mi = ty; mi < 64; mi += 4)
        tile[mi][tx] = proj[(size_t)((m0 + mi) * BSZ + b) * 2048 + 1024 + k * 64 + tx];
    __syncthreads();
    #pragma unroll
    for (int di = ty; di < 64; di += 4)
        vt[((size_t)jj * 80 + di) * 1024 + m0 + tx] = tile[tx][di];
    #pragma unroll
    for (int di = 64 + ty; di < 80; di += 4)
        vt[((size_t)jj * 80 + di) * 1024 + m0 + tx] = (di == 64) ? 0x3F80 : 0;
}

// ---- generic batched bf16 NT-GEMM (round-6-proven): 128x128 tile, BK=64,
// XOR chunk swizzle, global_load_lds width=16.
template<int OUT_F32, int RELU>
__global__ __launch_bounds__(256, 2) void gemm_bf16_nt(
    const u16* __restrict__ A, int lda, long long sA,
    const u16* __restrict__ B, int ldb, long long sB,
    const float* __restrict__ bias, int sBias,
    void* __restrict__ C, int ldc, long long sC,
    int K)
{
    __shared__ u16 As[128 * 64];
    __shared__ u16 Bs[128 * 64];
    const int t = threadIdx.x;
    const int z = blockIdx.z;
    const u16* Ab = A + (size_t)z * sA + (size_t)blockIdx.x * 128 * lda;
    const u16* Bb = B + (size_t)z * sB + (size_t)blockIdx.y * 128 * ldb;
    const int wave = t >> 6, lane = t & 63;
    const int wrow = (wave >> 1) << 6;
    const int wcol = (wave & 1) << 6;
    const int lr = lane & 15, lq = lane >> 4;
    const int srow = t >> 3;
    const int gchunk = (t & 7) ^ (srow & 7);
    const u16* ApG = Ab + (size_t)srow * lda + gchunk * 8;
    const u16* BpG = Bb + (size_t)srow * ldb + gchunk * 8;
    u16* AsD = &As[t * 8];
    u16* BsD = &Bs[t * 8];
    const int o0 = ((lq    ) ^ (lr & 7)) * 8;
    const int o1 = ((lq + 4) ^ (lr & 7)) * 8;

    f32x4 acc[4][4];
    #pragma unroll
    for (int i = 0; i < 4; i++)
        #pragma unroll
        for (int j = 0; j < 4; j++)
            acc[i][j] = (f32x4){0.f, 0.f, 0.f, 0.f};

    for (int k0 = 0; k0 < K; k0 += 64) {
        __syncthreads();
        #pragma unroll
        for (int j = 0; j < 4; j++) {
            load_lds16(ApG + (size_t)j * 32 * lda + k0, AsD + j * 2048);
            load_lds16(BpG + (size_t)j * 32 * ldb + k0, BsD + j * 2048);
        }
        __syncthreads();
        #pragma unroll
        for (int s = 0; s < 2; s++) {
            const int oo = s ? o1 : o0;
            bf16x8 af[4], bfv[4];
            #pragma unroll
            for (int i = 0; i < 4; i++)
                af[i] = *(const bf16x8*)&As[(wrow + i * 16 + lr) * 64 + oo];
            #pragma unroll
            for (int j = 0; j < 4; j++)
                bfv[j] = *(const bf16x8*)&Bs[(wcol + j * 16 + lr) * 64 + oo];
            #pragma unroll
            for (int i = 0; i < 4; i++)
                #pragma unroll
                for (int j = 0; j < 4; j++)
                    acc[i][j] = __builtin_amdgcn_mfma_f32_16x16x32_bf16(
                        af[i], bfv[j], acc[i][j], 0, 0, 0);
        }
    }

    const float* biasb = bias + (size_t)z * sBias;
    const size_t row0 = (size_t)blockIdx.x * 128 + wrow + lq * 4;
    const int col0 = blockIdx.y * 128 + wcol + lr;
    #pragma unroll
    for (int j = 0; j < 4; j++) {
        const int col = col0 + j * 16;
        const float bb = biasb[col];
        #pragma unroll
        for (int i = 0; i < 4; i++) {
            #pragma unroll
            for (int r = 0; r < 4; r++) {
                const size_t row = row0 + i * 16 + r;
                float v = acc[i][j][r] + bb;
                if (RELU) v = fmaxf(v, 0.f);
                const size_t idx = row * (size_t)ldc + col;
                if (OUT_F32) ((float*)C)[(size_t)z * sC + idx] = v;
                else         ((u16*)C)[(size_t)z * sC + idx] = f2bf(v);
            }
        }
    }
}

// ---- fused hid+logits+softmax+PV. R8 structure (counted split-drain, As2
// XOR layout) + LDS-traffic remap (the kernel is LDS-BW-bound: ~160 KB
// LDS traffic/block/K-iter vs 240 cyc of MFMA):
//  REMAP 1 (logits 1x4 m-split): each wave owns ALL 64 rows x its 64 m-cols
//    (was 2x2 of 32r x 128m). Bs redundancy 2x -> 1x (-32 KB/iter); As2
//    2x -> 4x (+16 KB). Net -16 KB. acc stays [4][4] = 64 regs.
//  REMAP 2 (hid quadrant-split): wave w computes rows (w&1)*32..+31 x
//    h (w>>1)*32..+31 (was: all waves over all 64 h). Each wave reads only
//    its 32-row half of W1s: W1s traffic 32 -> 16 KB/iter. Needs qf[2][2]
//    (+8 VGPRs). As2 quadrants cover exactly once.
// Total LDS traffic 160 -> 128 KB/block/K-iter (-20%).
// LDS: As2 8192 + W1s 8192 + Bs 32768 = 49152 B. 2 blocks/CU.
__global__ __launch_bounds__(256, 2) void fused_attn(
    const u16* __restrict__ proj,   // (4096, 2048) bf16; q-half = cols 0..1023
    const u16* __restrict__ w1t,    // (16, 1024, 64) bf16 [k][h][d]
    const float* __restrict__ b1,   // (16, 1024) fp32
    const u16* __restrict__ w2t,    // (16, 1024, 1024) bf16 [k][m][h]
    const float* __restrict__ b2,   // (16, 1024) fp32
    const u16* __restrict__ vt,     // (64, 80, 1024) bf16
    u16* __restrict__ attn)         // (4096, 1024) bf16
{
    __shared__ u16 As2[64 * 64];    // computed hid tile, XOR-chunk     (8 KB)
    __shared__ u16 W1s[64 * 64];    // w1t slice staging                (8 KB)
    __shared__ u16 BsPs[256 * 64];  // Bs: w2t 256m x 64k / Ps overlay (32 KB)
    const int t = threadIdx.x;
    const int kq = blockIdx.x;      // 0..15 (x-dim -> XCD affinity)
    const int pair = blockIdx.y;    // 0..31
    const int wave = t >> 6, lane = t & 63;
    const int lr = lane & 15, lq = lane >> 4;
    const int srow = t >> 3;                    // 0..31
    const int gch = (t & 7) ^ (srow & 7);       // XOR chunk swizzle
    const int o0 = ((lq    ) ^ (lr & 7)) * 8;
    const int o1 = ((lq + 4) ^ (lr & 7)) * 8;
    const int bv = kq >> 2;
    const int kvb = 4 * (kq & 3);               // kv = kvb + bq
    const int hrow = (wave & 1) * 32;           // hid quadrant: row base
    const int hcol = (wave >> 1) * 32;          // hid quadrant: h base
    const u16* wb  = w2t + (size_t)kq * 1048576 + (size_t)srow * 1024 + gch * 8;
    const u16* w1b = w1t + (size_t)kq * 65536   + (size_t)srow * 64   + gch * 8;
    const float* b1b = b1 + kq * 1024;
    const float* b2b = b2 + kq * 1024;

    for (int part = 0; part < 2; part++) {
        const int s = part ? (63 - pair) : pair;
        const int l0 = s << 4;
        const int nt = (s >> 4) + 1;
        // q A-fragments for the hid quadrant: wave w covers A-rows
        // rt = hrow + i*16 + r  (bq = 2*(w&1)+i), r = lane lr.
        // proj row = (l0+lr)*4 + bq, k-chunk = kq*64 + kk*32 + lq*8.
        bf16x8 qf[2][2];
        #pragma unroll
        for (int i = 0; i < 2; i++) {
            const u16* qsrc = proj
                + ((size_t)((l0 + lr) * 4 + 2 * (wave & 1) + i)) * 2048
                + kq * 64 + lq * 8;
            qf[i][0] = *(const bf16x8*)qsrc;
            qf[i][1] = *(const bf16x8*)(qsrc + 32);
        }
        f32x4 o[5];
        #pragma unroll
        for (int j = 0; j < 5; j++) o[j] = (f32x4){0.f, 0.f, 0.f, 0.f};

        for (int mt = 0; mt < nt; mt++) {
            // ---- logits tile 64(rows) x 256(m), K=1024 (hid on the fly)
            f32x4 acc[4][4];
            #pragma unroll
            for (int i = 0; i < 4; i++)
                #pragma unroll
                for (int j = 0; j < 4; j++)
                    acc[i][j] = (f32x4){0.f, 0.f, 0.f, 0.f};
            for (int k0 = 0; k0 < 1024; k0 += 64) {
                __syncthreads();   // prior logits/PV reads of Bs/Ps/As2 done
                float b1v[2];
                #pragma unroll
                for (int j2 = 0; j2 < 2; j2++)
                    b1v[j2] = b1b[k0 + hcol + j2 * 16 + lr];
                // W1s intrinsics FIRST (program order among intrinsics) so
                // vmcnt(8) always covers them; then the 8 Bs loads.
                load_lds16(w1b + (size_t)k0 * 64,        &W1s[t * 8]);
                load_lds16(w1b + (size_t)k0 * 64 + 2048, &W1s[2048 + t * 8]);
                #pragma unroll
                for (int j2 = 0; j2 < 8; j2++)
                    load_lds16(wb + (size_t)(mt * 256 + j2 * 32) * 1024 + k0,
                               &BsPs[j2 * 2048 + t * 8]);
                // counted wait: W1s (+b1) done, 8 Bs loads stay in flight
                asm volatile("s_waitcnt vmcnt(8)" ::: "memory");
                __builtin_amdgcn_s_barrier();
                __builtin_amdgcn_sched_barrier(0);
                // -- hid quadrant: rows hrow+i*16+(lq*4+rg), h hcol+j2*16+lr
                //    (runs while Bs streams into LDS)
                {
                    f32x4 ah[2][2];
                    #pragma unroll
                    for (int i = 0; i < 2; i++)
                        #pragma unroll
                        for (int j2 = 0; j2 < 2; j2++)
                            ah[i][j2] = (f32x4){0.f, 0.f, 0.f, 0.f};
                    #pragma unroll
                    for (int kk = 0; kk < 2; kk++) {
                        const int oo = kk ? o1 : o0;
                        #pragma unroll
                        for (int j2 = 0; j2 < 2; j2++) {
                            const bf16x8 bw = *(const bf16x8*)
                                &W1s[(hcol + j2 * 16 + lr) * 64 + oo];
                            #pragma unroll
                            for (int i = 0; i < 2; i++)
                                ah[i][j2] = __builtin_amdgcn_mfma_f32_16x16x32_bf16(
                                    qf[i][kk], bw, ah[i][j2], 0, 0, 0);
                        }
                    }
                    #pragma unroll
                    for (int i = 0; i < 2; i++) {
                        const int rtb = hrow + i * 16 + lq * 4;
                        #pragma unroll
                        for (int j2 = 0; j2 < 2; j2++) {
                            const int ch = (hcol >> 3) + j2 * 2 + (lr >> 3);
                            #pragma unroll
                            for (int rg = 0; rg < 4; rg++) {
                                const float v = fmaxf(ah[i][j2][rg] + b1v[j2], 0.f);
                                const int row = rtb + rg;
                                As2[row * 64 + ((ch ^ (row & 7)) << 3) +
                                    (lr & 7)] = f2bf(v);
                            }
                        }
                    }
                }
                // full drain: Bs landed + As2 ds_writes visible to all waves
                asm volatile("s_waitcnt vmcnt(0) lgkmcnt(0)" ::: "memory");
                __builtin_amdgcn_s_barrier();
                __builtin_amdgcn_sched_barrier(0);
                // -- logits: wave owns ALL 64 rows x m-cols wave*64..+63
                #pragma unroll
                for (int s2 = 0; s2 < 2; s2++) {
                    const int oo = s2 ? o1 : o0;
                    bf16x8 af[4], bfv[4];
                    #pragma unroll
                    for (int i = 0; i < 4; i++)
                        af[i] = *(const bf16x8*)
                            &As2[(i * 16 + lr) * 64 + oo];
                    #pragma unroll
                    for (int j = 0; j < 4; j++)
                        bfv[j] = *(const bf16x8*)
                            &BsPs[(wave * 64 + j * 16 + lr) * 64 + oo];
                    #pragma unroll
                    for (int i = 0; i < 4; i++)
                        #pragma unroll
                        for (int j = 0; j < 4; j++)
                            acc[i][j] = __builtin_amdgcn_mfma_f32_16x16x32_bf16(
                                af[i], bfv[j], acc[i][j], 0, 0, 0);
                }
            }
            // ---- +b2, causal compare, exp -> Ps (bf16, overlaid on Bs)
            __syncthreads();   // all waves' last Bs MFMA reads complete
            float b2v[4];
            #pragma unroll
            for (int j = 0; j < 4; j++)
                b2v[j] = b2b[mt * 256 + wave * 64 + j * 16 + lr];
            #pragma unroll
            for (int i = 0; i < 4; i++) {
                #pragma unroll
                for (int j = 0; j < 4; j++) {
                    const int cp = wave * 64 + j * 16 + lr;
                    const int m = mt * 256 + cp;
                    const int cb = cp & 7;       // elem within 8-chunk
                    const int cc = cp >> 3;      // chunk index
                    #pragma unroll
                    for (int rr = 0; rr < 4; rr++) {
                        const int rt = i * 16 + lq * 4 + rr;
                        const int l = l0 + lq * 4 + rr;   // rt&15 == lq*4+rr
                        const float e = __expf(acc[i][j][rr] + b2v[j]);
                        BsPs[rt * 256 + cb + ((cc ^ (rt & 7)) << 3)]
                            = (m <= l) ? f2bf(e) : (u16)0;
                    }
                }
            }
            __syncthreads();
            // ---- O += P @ V^T: wave w owns bq = w (rows w*16..w*16+15)
            {
                const u16* vbb = vt + (size_t)(kq * 4 + wave) * 80 * 1024
                               + (size_t)mt * 256 + lq * 8;
                const int rt = wave * 16 + lr;
                #pragma unroll
                for (int kc = 0; kc < 8; kc++) {
                    const bf16x8 a = *(const bf16x8*)
                        &BsPs[rt * 256 + ((((kc << 2) + lq) ^ (rt & 7)) << 3)];
                    #pragma unroll
                    for (int j = 0; j < 5; j++) {
                        const bf16x8 b = *(const bf16x8*)
                            (vbb + (size_t)(j * 16 + lr) * 1024 + kc * 32);
                        o[j] = __builtin_amdgcn_mfma_f32_16x16x32_bf16(
                            a, b, o[j], 0, 0, 0);
                    }
                }
            }
        }
        // ---- normalize by rowsum (ones-column d=64 -> o[4], lanes lr==0)
        {
            const int bq = wave;
            float sden[4];
            #pragma unroll
            for (int rr = 0; rr < 4; rr++)
                sden[rr] = __shfl(o[4][rr], lq << 4);
            #pragma unroll
            for (int j = 0; j < 4; j++) {
                #pragma unroll
                for (int rr = 0; rr < 4; rr++) {
                    const int l = l0 + lq * 4 + rr;
                    attn[(size_t)(l * BSZ + bv) * 1024 + (kvb + bq) * 64 + j * 16 + lr]
                        = f2bf(o[j][rr] / sden[rr]);
                }
            }
        }
    }
}

extern "C" void kernel_launch(void* const* d_in, const int* in_sizes, int n_in,
                              void* d_out, int out_size, void* d_ws, size_t ws_size,
                              hipStream_t stream)
{
    (void)in_sizes; (void)n_in; (void)out_size; (void)ws_size;
    const float* x  = (const float*)d_in[0];
    const float* Wi = (const float*)d_in[2];
    const float* bi = (const float*)d_in[3];
    const float* w1 = (const float*)d_in[4];
    const float* b1 = (const float*)d_in[5];
    const float* w2 = (const float*)d_in[6];
    const float* b2 = (const float*)d_in[7];
    const float* Wo = (const float*)d_in[8];
    const float* bo = (const float*)d_in[9];

    // ws layout (bf16 elems): 46 MB used <= 256 MiB (hid no longer stored)
    u16* x_b    = (u16*)d_ws;                  // 4096x1024       = 4M
    u16* Wi_b   = x_b    + (size_t)4194304;    // 2048x1024       = 2M
    u16* w1t    = Wi_b   + (size_t)2097152;    // 16 x 1024x64    = 1M
    u16* w2t    = w1t    + (size_t)1048576;    // 16 x 1024x1024  = 16M
    u16* Wo_b   = w2t    + (size_t)16777216;   // 1024x1024       = 1M
    u16* proj_b = Wo_b   + (size_t)1048576;    // 4096x2048       = 8M
    u16* attn_b = proj_b + (size_t)8388608;    // 4096x1024       = 4M
    u16* vt     = attn_b + (size_t)4194304;    // 64 x 80 x 1024  = 5M

    // ---- prep
    cvt_all<<<7168, 256, 0, stream>>>(x, Wi, Wo, x_b, Wi_b, Wo_b);
    transpose_cvt<<<dim3(32,  2, 16), 256, 0, stream>>>(w1, w1t, 64,   1024);
    transpose_cvt<<<dim3(32, 32, 16), 256, 0, stream>>>(w2, w2t, 1024, 1024);

    // ---- proj = x @ Wi.T + bi  -> bf16 (4096 x 2048)
    gemm_bf16_nt<0, 0><<<dim3(32, 16, 1), 256, 0, stream>>>(
        x_b, 1024, 0, Wi_b, 1024, 0, bi, 0, (void*)proj_b, 2048, 0, 1024);

    // ---- vt[j][d(80)][m] from proj's v-half (with ones-column at d=64)
    build_vt<<<dim3(16, 64), 256, 0, stream>>>(proj_b, vt);

    // ---- fused hid + logits + softmax + PV (LDS-traffic remap: 1x4 m-split
    //      logits + quadrant-split hid; -20% LDS bytes/iter)
    fused_attn<<<dim3(16, 32), 256, 0, stream>>>(
        proj_b, w1t, b1, w2t, b2, vt, attn_b);

    // ---- out = attn @ Wo.T + bo -> fp32 (4096 x 1024)
    gemm_bf16_nt<1, 0><<<dim3(32, 8, 1), 256, 0, stream>>>(
        attn_b, 1024, 0, Wo_b, 1024, 0, bo, 0, d_out, 1024, 0, 1024);
}